// Round 16
// baseline (130.300 us; speedup 1.0000x reference)
//
#include <hip/hip_runtime.h>
#include <hip/hip_bf16.h>
#include <math.h>

#define NPTS 524288
#define HDIM 256
#define NBLK1 (NPTS / 256)        // 2048 blocks, 1 point per thread
#define STEPS 100

constexpr float DXF        = (float)(20.0 / (NPTS - 1));
constexpr float DTF        = 0.01f;
constexpr float SQRT2DT    = 0.14142135623730951f;       // np.float32(sqrt(2*DT))
constexpr float TWO_LOG2E  = 2.8853900817779268f;        // 2*log2(e)
constexpr float LN2_O_2DX  = (float)(0.6931471805599453 / (2.0 * (20.0 / (NPTS - 1))));

typedef float v2f __attribute__((ext_vector_type(2)));

static __device__ __forceinline__ v2f vfma(v2f a, v2f b, v2f c) {
#if __has_builtin(__builtin_elementwise_fma)
    return __builtin_elementwise_fma(a, b, c);
#else
    v2f r; r.x = fmaf(a.x, b.x, c.x); r.y = fmaf(a.y, b.y, c.y); return r;
#endif
}

// ---------------------------------------------------------------------------
// Kernel 0: fold constants. wk (256 floats each): w1k|b1k|w20|w21|wg0|wg1
// ---------------------------------------------------------------------------
__global__ void qpe_prep(const float* __restrict__ W1, const float* __restrict__ b1,
                         const float* __restrict__ W2, float* __restrict__ wk)
{
    const int h = threadIdx.x;
    const float w1  = W1[h];
    const float w20 = W2[2*h];
    const float w21 = W2[2*h + 1];
    const float w1s = w1 * w1;
    wk[h]        = w1 * TWO_LOG2E;
    wk[256 + h]  = b1[h] * TWO_LOG2E;
    wk[512 + h]  = w20;
    wk[768 + h]  = w21;
    wk[1024 + h] = w20 * w1s;
    wk[1280 + h] = w21 * w1s;
}

// ---------------------------------------------------------------------------
// Kernel 1: 1 pt/thread, 2048 blocks, dual h-stream packed math (R13) with
// ONE change: weights staged in LDS instead of streamed via scalar s_loads.
// Theory: the ~15 us stall floor capping VALUBusy at ~65% in every packed
// variant is SMEM latency -- at 96 SGPRs the compiler holds exactly one
// unrolled block's weights (6 streams x 16 floats), so s_loads can't
// double-buffer. ds_reads into VGPRs (24 used, 64 budget at 8 waves/SIMD)
// pipeline deep, and same-address LDS reads broadcast for free.
// ---------------------------------------------------------------------------
__global__ __launch_bounds__(256) void qpe_main(
    const float* __restrict__ x,  const float* __restrict__ V,
    const float* __restrict__ wk, const float* __restrict__ b2,
    float* __restrict__ out,      float* __restrict__ lp2,
    float* __restrict__ pdens,    float* __restrict__ pnd)
{
    __shared__ float wlds[1536];
    const int tid = threadIdx.x;
    #pragma unroll
    for (int k = 0; k < 6; ++k)
        wlds[k * 256 + tid] = wk[k * 256 + tid];
    __syncthreads();

    const int i = blockIdx.x * 256 + tid;
    const float xi = x[i];
    const float Vi = V[i];

    const v2f* w1k2 = (const v2f*)(wlds);
    const v2f* b1k2 = (const v2f*)(wlds + 256);
    const v2f* w202 = (const v2f*)(wlds + 512);
    const v2f* w212 = (const v2f*)(wlds + 768);
    const v2f* wg02 = (const v2f*)(wlds + 1024);
    const v2f* wg12 = (const v2f*)(wlds + 1280);

    const v2f x2   = {xi, xi};
    const v2f one2 = {1.0f, 1.0f};
    const v2f m2   = {-2.0f, -2.0f};
    v2f p0A = {0.f,0.f}, p1A = {0.f,0.f}, a0A = {0.f,0.f}, a1A = {0.f,0.f};
    v2f p0B = {0.f,0.f}, p1B = {0.f,0.f}, a0B = {0.f,0.f}, a1B = {0.f,0.f};

    #pragma unroll 4
    for (int j = 0; j < HDIM / 4; ++j) {
        const int jb = j + HDIM / 4;                 // second h-stream
        const v2f uA = vfma(x2, w1k2[j],  b1k2[j]);
        const v2f uB = vfma(x2, w1k2[jb], b1k2[jb]);
        v2f eA, eB;
        eA.x = __builtin_amdgcn_exp2f(uA.x); eA.y = __builtin_amdgcn_exp2f(uA.y);
        eB.x = __builtin_amdgcn_exp2f(uB.x); eB.y = __builtin_amdgcn_exp2f(uB.y);
        const v2f dA = eA + one2;
        const v2f dB = eB + one2;
        v2f rA, rB;
        rA.x = __builtin_amdgcn_rcpf(dA.x); rA.y = __builtin_amdgcn_rcpf(dA.y);
        rB.x = __builtin_amdgcn_rcpf(dB.x); rB.y = __builtin_amdgcn_rcpf(dB.y);
        const v2f tA = vfma(m2, rA, one2);           // tanh
        const v2f tB = vfma(m2, rB, one2);
        const v2f oA = vfma(-tA, tA, one2);          // 1 - t^2
        const v2f oB = vfma(-tB, tB, one2);
        const v2f gA = tA * oA;                      // t(1-t^2)
        const v2f gB = tB * oB;
        p0A = vfma(w202[j],  tA, p0A);
        p1A = vfma(w212[j],  tA, p1A);
        a0A = vfma(wg02[j],  gA, a0A);
        a1A = vfma(wg12[j],  gA, a1A);
        p0B = vfma(w202[jb], tB, p0B);
        p1B = vfma(w212[jb], tB, p1B);
        a0B = vfma(wg02[jb], gB, a0B);
        a1B = vfma(wg12[jb], gB, a1B);
    }

    const v2f p0 = p0A + p0B;
    const v2f p1 = p1A + p1B;
    const v2f a0 = a0A + a0B;
    const v2f a1 = a1A + a1B;

    const float psi0 = p0.x + p0.y + b2[0];
    const float psi1 = p1.x + p1.y + b2[1];
    const float ta0  = a0.x + a0.y;
    const float ta1  = a1.x + a1.y;

    const float hp0 = fmaf(Vi, psi0, ta0);          // h_psi = K*lap + V*psi
    const float hp1 = fmaf(Vi, psi1, ta1);
    reinterpret_cast<float2*>(out)[i] = make_float2(hp0, hp1);

    const float nd = fmaf(psi0, psi0, psi1 * psi1);
    lp2[i] = __builtin_amdgcn_logf(nd);             // log2(nd)

    float dens = fmaf(psi0, hp0, psi1 * hp1);
    float ndr  = nd;
    #pragma unroll
    for (int off = 32; off; off >>= 1) {
        dens += __shfl_down(dens, off);
        ndr  += __shfl_down(ndr, off);
    }
    __shared__ float sd[4], sn[4];
    const int lane = tid & 63;
    const int wid  = tid >> 6;
    if (lane == 0) { sd[wid] = dens; sn[wid] = ndr; }
    __syncthreads();
    if (tid == 0) {
        pdens[blockIdx.x] = sd[0] + sd[1] + sd[2] + sd[3];
        pnd[blockIdx.x]   = sn[0] + sn[1] + sn[2] + sn[3];
    }
}

// ---------------------------------------------------------------------------
// Kernel 2, 2 blocks (unchanged from R13):
//   block0          : reduce 2048 partials -> energy
//   block1 wave0.l0 : 100-step lookup walk on lp2
//   block1 waves1-3 : two-phase ring warm (inner 256 KB, then 512 KB)
// ---------------------------------------------------------------------------
__global__ __launch_bounds__(256) void qpe_tail(
    const float* __restrict__ x,     const float* __restrict__ lp2,
    const float* __restrict__ pdens, const float* __restrict__ pnd,
    const float* __restrict__ noise, const int* __restrict__ init_idx,
    float* __restrict__ out,         float* __restrict__ dummy)
{
    const int tid = threadIdx.x;
    if (blockIdx.x == 0) {
        float d = 0.f, n = 0.f;
        #pragma unroll
        for (int k = 0; k < 8; ++k) {
            d += pdens[tid + 256 * k];
            n += pnd[tid + 256 * k];
        }
        #pragma unroll
        for (int off = 32; off; off >>= 1) {
            d += __shfl_down(d, off);
            n += __shfl_down(n, off);
        }
        __shared__ float sd[4], sn[4];
        const int lane = tid & 63;
        const int wid  = tid >> 6;
        if (lane == 0) { sd[wid] = d; sn[wid] = n; }
        __syncthreads();
        if (tid == 0) {
            const float Sd = sd[0] + sd[1] + sd[2] + sd[3];
            const float Sn = sn[0] + sn[1] + sn[2] + sn[3];
            out[2 * NPTS] = __fdiv_rn(Sd * DXF, fmaf(Sn, DXF, 1e-8f));
        }
        return;
    }

    if (tid == 0) {
        int c = init_idx[0];
        float zn = noise[0];
        for (int t = 0; t < STEPS; ++t) {
            const float zs = __fmul_rn(zn, SQRT2DT);
            const int tn = (t + 1 < STEPS) ? t + 1 : t;
            zn = noise[tn];                  // prefetch next step's noise
            float s = 0.0f;
            if (c > 0 && c < NPTS - 1) {
                const float l2m = lp2[c - 1];
                const float l2p = lp2[c + 1];
                s = __fmul_rn(__fsub_rn(l2p, l2m), LN2_O_2DX);
            }
            const float a = __fadd_rn(__fmul_rn(s, DTF), zs);
            const int shift = (int)__fdiv_rn(a, DXF);
            c += shift;
            c = c < 0 ? 0 : (c > NPTS - 1 ? NPTS - 1 : c);
        }
        out[2 * NPTS + 1] = x[c];
    } else if (tid >= 64) {
        const int l = tid - 64;              // 0..191
        const int c0 = init_idx[0];
        float acc = 0.f;

        // phase 1: inner 256 KB (16K float4) centered on c0
        int s4i = c0 / 4 - 8192;
        if (s4i < 0) s4i = 0;
        if (s4i > NPTS / 4 - 16384) s4i = NPTS / 4 - 16384;
        const float4* __restrict__ srci = (const float4*)lp2 + s4i;
        #pragma unroll 8
        for (int k = l; k < 16384; k += 192) {
            const float4 v = srci[k];
            acc += v.x + v.y + v.z + v.w;
        }

        // phase 2: full 512 KB (32K float4) window
        int s4 = c0 / 4 - 16384;
        if (s4 < 0) s4 = 0;
        if (s4 > NPTS / 4 - 32768) s4 = NPTS / 4 - 32768;
        const float4* __restrict__ src = (const float4*)lp2 + s4;
        #pragma unroll 8
        for (int k = l; k < 32768; k += 192) {
            const float4 v = src[k];
            acc += v.x + v.y + v.z + v.w;
        }
        if (acc == 123456.789f) dummy[0] = acc;   // keep loads alive
    }
}

// ---------------------------------------------------------------------------
extern "C" void kernel_launch(void* const* d_in, const int* in_sizes, int n_in,
                              void* d_out, int out_size, void* d_ws, size_t ws_size,
                              hipStream_t stream) {
    const float* x        = (const float*)d_in[0];
    const float* V        = (const float*)d_in[1];
    const float* W1       = (const float*)d_in[2];
    const float* b1       = (const float*)d_in[3];
    const float* W2       = (const float*)d_in[4];
    const float* b2       = (const float*)d_in[5];
    const float* noise    = (const float*)d_in[6];
    const int*   init_idx = (const int*)d_in[7];

    float* out = (float*)d_out;
    float* ws  = (float*)d_ws;

    float* lp2   = ws;                      // N floats (2 MB)
    float* wk    = ws + NPTS;               // 1536 (pad to 2048)
    float* pdens = ws + NPTS + 2048;        // 2048
    float* pnd   = ws + NPTS + 4096;        // 2048
    float* dummy = ws + NPTS + 6144;        // 1

    qpe_prep<<<1, 256, 0, stream>>>(W1, b1, W2, wk);
    qpe_main<<<NBLK1, 256, 0, stream>>>(x, V, wk, b2, out, lp2, pdens, pnd);
    qpe_tail<<<2, 256, 0, stream>>>(x, lp2, pdens, pnd, noise, init_idx,
                                    out, dummy);
}

// Round 19
// 122.497 us; speedup vs baseline: 1.0637x; 1.0637x over previous
//
#include <hip/hip_runtime.h>
#include <hip/hip_bf16.h>
#include <math.h>

#define NPTS 524288
#define HDIM 256
#define NBLK2 (NPTS / 512)        // 1024 blocks, 2 adjacent points per thread
#define STEPS 100

constexpr float DXF        = (float)(20.0 / (NPTS - 1));
constexpr float DTF        = 0.01f;
constexpr float SQRT2DT    = 0.14142135623730951f;       // np.float32(sqrt(2*DT))
constexpr float TWO_LOG2E  = 2.8853900817779268f;        // 2*log2(e)
constexpr float LN2_O_2DX  = (float)(0.6931471805599453 / (2.0 * (20.0 / (NPTS - 1))));

typedef float v2f __attribute__((ext_vector_type(2)));

static __device__ __forceinline__ v2f vfma(v2f a, v2f b, v2f c) {
#if __has_builtin(__builtin_elementwise_fma)
    return __builtin_elementwise_fma(a, b, c);
#else
    v2f r; r.x = fmaf(a.x, b.x, c.x); r.y = fmaf(a.y, b.y, c.y); return r;
#endif
}

// ---------------------------------------------------------------------------
// Kernel 0: fold constants. wk (256 floats each): w1k|b1k|w20|w21|wg0|wg1|ck
//   ck = 2^(w1k*DX): per-grid-step multiplier for the incremental exp.
// ---------------------------------------------------------------------------
__global__ void qpe_prep(const float* __restrict__ W1, const float* __restrict__ b1,
                         const float* __restrict__ W2, float* __restrict__ wk)
{
    const int h = threadIdx.x;
    const float w1  = W1[h];
    const float w20 = W2[2*h];
    const float w21 = W2[2*h + 1];
    const float w1s = w1 * w1;
    const float w1k = w1 * TWO_LOG2E;
    wk[h]        = w1k;
    wk[256 + h]  = b1[h] * TWO_LOG2E;
    wk[512 + h]  = w20;
    wk[768 + h]  = w21;
    wk[1024 + h] = w20 * w1s;
    wk[1280 + h] = w21 * w1s;
    wk[1536 + h] = exp2f(w1k * DXF);
}

// ---------------------------------------------------------------------------
// Kernel 1: 2 adjacent points/thread (the best-measured geometry, R5) with
// HALVED transcendental count -- the measured floor of every variant so far:
//   eB = eA * ck      (grid step in exp2 domain; 1 pk-mul replaces 2 exp2)
//   r  = rcp(dA*dB); 1/dA = dB*r; 1/dB = dA*r   (1 rcp replaces 2)
// Per (2h x 2pt): 4 trans + 21 pk vs R5's 8 trans + 18 pk.
// Overflow note: m=inf => r=0 => t=1, exactly tanh saturation, still correct.
// ---------------------------------------------------------------------------
__global__ __launch_bounds__(256) void qpe_main(
    const float* __restrict__ x,  const float* __restrict__ V,
    const float* __restrict__ wk, const float* __restrict__ b2,
    float* __restrict__ out,      float* __restrict__ lp2,
    float* __restrict__ pdens,    float* __restrict__ pnd)
{
    const int i = blockIdx.x * 256 + threadIdx.x;     // pair index
    const float2 xv = reinterpret_cast<const float2*>(x)[i];
    const float2 Vv = reinterpret_cast<const float2*>(V)[i];

    const v2f* __restrict__ w1k2 = (const v2f*)(wk);
    const v2f* __restrict__ b1k2 = (const v2f*)(wk + 256);
    const v2f* __restrict__ w202 = (const v2f*)(wk + 512);
    const v2f* __restrict__ w212 = (const v2f*)(wk + 768);
    const v2f* __restrict__ wg02 = (const v2f*)(wk + 1024);
    const v2f* __restrict__ wg12 = (const v2f*)(wk + 1280);
    const v2f* __restrict__ ck2  = (const v2f*)(wk + 1536);

    const v2f xa   = {xv.x, xv.x};                    // point A (even index)
    const v2f one2 = {1.0f, 1.0f};
    const v2f m2   = {-2.0f, -2.0f};
    v2f pa0 = {0.f,0.f}, pa1 = {0.f,0.f}, aa0 = {0.f,0.f}, aa1 = {0.f,0.f};
    v2f pb0 = {0.f,0.f}, pb1 = {0.f,0.f}, ab0 = {0.f,0.f}, ab1 = {0.f,0.f};

    #pragma unroll 4
    for (int j = 0; j < HDIM / 2; ++j) {
        const v2f w1 = w1k2[j];
        const v2f bb = b1k2[j];
        const v2f cc = ck2[j];
        const v2f uA = vfma(xa, w1, bb);
        v2f eA;
        eA.x = __builtin_amdgcn_exp2f(uA.x);
        eA.y = __builtin_amdgcn_exp2f(uA.y);          // 2 trans
        const v2f eB = eA * cc;                       // point B: 1 pk-mul
        const v2f dA = eA + one2;
        const v2f dB = eB + one2;
        const v2f m  = dA * dB;
        v2f r;
        r.x = __builtin_amdgcn_rcpf(m.x);
        r.y = __builtin_amdgcn_rcpf(m.y);             // 2 trans (batched)
        const v2f rA = dB * r;                        // 1/dA
        const v2f rB = dA * r;                        // 1/dB
        const v2f tA = vfma(m2, rA, one2);            // tanh
        const v2f tB = vfma(m2, rB, one2);
        const v2f oA = vfma(-tA, tA, one2);           // 1 - t^2
        const v2f oB = vfma(-tB, tB, one2);
        const v2f gA = tA * oA;                       // t(1-t^2)
        const v2f gB = tB * oB;
        const v2f w20 = w202[j], w21 = w212[j];
        const v2f g0  = wg02[j], g1  = wg12[j];
        pa0 = vfma(w20, tA, pa0);  pa1 = vfma(w21, tA, pa1);
        aa0 = vfma(g0,  gA, aa0);  aa1 = vfma(g1,  gA, aa1);
        pb0 = vfma(w20, tB, pb0);  pb1 = vfma(w21, tB, pb1);
        ab0 = vfma(g0,  gB, ab0);  ab1 = vfma(g1,  gB, ab1);
    }

    const float b20 = b2[0], b21 = b2[1];
    const float psiA0 = pa0.x + pa0.y + b20;
    const float psiA1 = pa1.x + pa1.y + b21;
    const float psiB0 = pb0.x + pb0.y + b20;
    const float psiB1 = pb1.x + pb1.y + b21;
    const float taA0 = aa0.x + aa0.y, taA1 = aa1.x + aa1.y;
    const float taB0 = ab0.x + ab0.y, taB1 = ab1.x + ab1.y;

    const float hpA0 = fmaf(Vv.x, psiA0, taA0);       // h_psi = K*lap + V*psi
    const float hpA1 = fmaf(Vv.x, psiA1, taA1);
    const float hpB0 = fmaf(Vv.y, psiB0, taB0);
    const float hpB1 = fmaf(Vv.y, psiB1, taB1);
    float4 o4; o4.x = hpA0; o4.y = hpA1; o4.z = hpB0; o4.w = hpB1;
    reinterpret_cast<float4*>(out)[i] = o4;

    const float ndA = fmaf(psiA0, psiA0, psiA1 * psiA1);
    const float ndB = fmaf(psiB0, psiB0, psiB1 * psiB1);
    float2 l2;
    l2.x = __builtin_amdgcn_logf(ndA);                // log2(nd)
    l2.y = __builtin_amdgcn_logf(ndB);
    reinterpret_cast<float2*>(lp2)[i] = l2;

    float dens = fmaf(psiA0, hpA0, psiA1 * hpA1) + fmaf(psiB0, hpB0, psiB1 * hpB1);
    float ndr  = ndA + ndB;
    #pragma unroll
    for (int off = 32; off; off >>= 1) {
        dens += __shfl_down(dens, off);
        ndr  += __shfl_down(ndr, off);
    }
    __shared__ float sd[4], sn[4];
    const int lane = threadIdx.x & 63;
    const int wid  = threadIdx.x >> 6;
    if (lane == 0) { sd[wid] = dens; sn[wid] = ndr; }
    __syncthreads();
    if (threadIdx.x == 0) {
        pdens[blockIdx.x] = sd[0] + sd[1] + sd[2] + sd[3];
        pnd[blockIdx.x]   = sn[0] + sn[1] + sn[2] + sn[3];
    }
}

// ---------------------------------------------------------------------------
// Kernel 2, 2 blocks (tail structure unchanged; block0 now sums 1024
// partials):
//   block0          : reduce partials -> energy
//   block1 wave0.l0 : 100-step lookup walk on lp2
//   block1 waves1-3 : two-phase ring warm (inner 256 KB, then 512 KB)
// ---------------------------------------------------------------------------
__global__ __launch_bounds__(256) void qpe_tail(
    const float* __restrict__ x,     const float* __restrict__ lp2,
    const float* __restrict__ pdens, const float* __restrict__ pnd,
    const float* __restrict__ noise, const int* __restrict__ init_idx,
    float* __restrict__ out,         float* __restrict__ dummy)
{
    const int tid = threadIdx.x;
    if (blockIdx.x == 0) {
        float d = 0.f, n = 0.f;
        #pragma unroll
        for (int k = 0; k < 4; ++k) {
            d += pdens[tid + 256 * k];
            n += pnd[tid + 256 * k];
        }
        #pragma unroll
        for (int off = 32; off; off >>= 1) {
            d += __shfl_down(d, off);
            n += __shfl_down(n, off);
        }
        __shared__ float sd[4], sn[4];
        const int lane = tid & 63;
        const int wid  = tid >> 6;
        if (lane == 0) { sd[wid] = d; sn[wid] = n; }
        __syncthreads();
        if (tid == 0) {
            const float Sd = sd[0] + sd[1] + sd[2] + sd[3];
            const float Sn = sn[0] + sn[1] + sn[2] + sn[3];
            out[2 * NPTS] = __fdiv_rn(Sd * DXF, fmaf(Sn, DXF, 1e-8f));
        }
        return;
    }

    if (tid == 0) {
        int c = init_idx[0];
        float zn = noise[0];
        for (int t = 0; t < STEPS; ++t) {
            const float zs = __fmul_rn(zn, SQRT2DT);
            const int tn = (t + 1 < STEPS) ? t + 1 : t;
            zn = noise[tn];                  // prefetch next step's noise
            float s = 0.0f;
            if (c > 0 && c < NPTS - 1) {
                const float l2m = lp2[c - 1];
                const float l2p = lp2[c + 1];
                s = __fmul_rn(__fsub_rn(l2p, l2m), LN2_O_2DX);
            }
            const float a = __fadd_rn(__fmul_rn(s, DTF), zs);
            const int shift = (int)__fdiv_rn(a, DXF);
            c += shift;
            c = c < 0 ? 0 : (c > NPTS - 1 ? NPTS - 1 : c);
        }
        out[2 * NPTS + 1] = x[c];
    } else if (tid >= 64) {
        const int l = tid - 64;              // 0..191
        const int c0 = init_idx[0];
        float acc = 0.f;

        // phase 1: inner 256 KB (16K float4) centered on c0
        int s4i = c0 / 4 - 8192;
        if (s4i < 0) s4i = 0;
        if (s4i > NPTS / 4 - 16384) s4i = NPTS / 4 - 16384;
        const float4* __restrict__ srci = (const float4*)lp2 + s4i;
        #pragma unroll 8
        for (int k = l; k < 16384; k += 192) {
            const float4 v = srci[k];
            acc += v.x + v.y + v.z + v.w;
        }

        // phase 2: full 512 KB (32K float4) window
        int s4 = c0 / 4 - 16384;
        if (s4 < 0) s4 = 0;
        if (s4 > NPTS / 4 - 32768) s4 = NPTS / 4 - 32768;
        const float4* __restrict__ src = (const float4*)lp2 + s4;
        #pragma unroll 8
        for (int k = l; k < 32768; k += 192) {
            const float4 v = src[k];
            acc += v.x + v.y + v.z + v.w;
        }
        if (acc == 123456.789f) dummy[0] = acc;   // keep loads alive
    }
}

// ---------------------------------------------------------------------------
extern "C" void kernel_launch(void* const* d_in, const int* in_sizes, int n_in,
                              void* d_out, int out_size, void* d_ws, size_t ws_size,
                              hipStream_t stream) {
    const float* x        = (const float*)d_in[0];
    const float* V        = (const float*)d_in[1];
    const float* W1       = (const float*)d_in[2];
    const float* b1       = (const float*)d_in[3];
    const float* W2       = (const float*)d_in[4];
    const float* b2       = (const float*)d_in[5];
    const float* noise    = (const float*)d_in[6];
    const int*   init_idx = (const int*)d_in[7];

    float* out = (float*)d_out;
    float* ws  = (float*)d_ws;

    float* lp2   = ws;                      // N floats (2 MB)
    float* wk    = ws + NPTS;               // 1792 (pad to 2048)
    float* pdens = ws + NPTS + 2048;        // 1024
    float* pnd   = ws + NPTS + 4096;        // 1024
    float* dummy = ws + NPTS + 6144;        // 1

    qpe_prep<<<1, 256, 0, stream>>>(W1, b1, W2, wk);
    qpe_main<<<NBLK2, 256, 0, stream>>>(x, V, wk, b2, out, lp2, pdens, pnd);
    qpe_tail<<<2, 256, 0, stream>>>(x, lp2, pdens, pnd, noise, init_idx,
                                    out, dummy);
}